// Round 6
// baseline (314.515 us; speedup 1.0000x reference)
//
#include <hip/hip_runtime.h>
#include <hip/hip_cooperative_groups.h>

namespace cg = cooperative_groups;

#define INF 256
#define OUTF 128
#define NEG_SLOPE 0.2f

// ============================ cooperative path ============================
// One kernel, 4 phases separated by grid.sync():
//  A: blocks 0..7 compute u[c][i] = sum_o W[h,i,o]*a[h,kind*128+o] (c=kind*4+h);
//     other blocks zero [denom|wsum|flag].
//  B: s_src[n].h = x[n,:]·u[h], s_dst[n].h = x[n,:]·u[4+h] (wave per node);
//     plus self-loop scan -> flag[s]=1.
//  C: edges with flagged dst: denom[d,h] += exp(lrelu(s)); wsum for self-edges.
//     Max-shift elided: logits bounded (~±17), expf fits fp32; cancels in ratio.
//  D: write ENTIRE output: zero rows streamed; flagged rows (~48) = dg*(x[n]@W[h]).
__global__ __launch_bounds__(256, 4)
void k_fused(const float* __restrict__ x, const float* __restrict__ W,
             const float* __restrict__ a,
             const int* __restrict__ src, const int* __restrict__ dst,
             int N, int E,
             float* __restrict__ u,
             float4* __restrict__ ssrc, float4* __restrict__ sdst,
             float* __restrict__ denom, float* __restrict__ wsum,
             int* __restrict__ flag,
             float4* __restrict__ zbase, int zquads,
             float2* __restrict__ out2) {
    cg::grid_group grid = cg::this_grid();
    const int bid = blockIdx.x, nb = gridDim.x, t = threadIdx.x;
    __shared__ float uL[8][INF];
    __shared__ float xL[INF];

    // ---- Phase A ----
    if (bid < 8) {
        int kind = bid >> 2, h = bid & 3;
        if (t < OUTF) xL[t] = a[h * 2 * OUTF + kind * OUTF + t];
        __syncthreads();
        const float* Wr = W + ((size_t)(h * INF + t)) * OUTF;
        float acc = 0.f;
        #pragma unroll 8
        for (int o = 0; o < OUTF; ++o) acc += Wr[o] * xL[o];
        u[bid * INF + t] = acc;
        __syncthreads();
    } else {
        for (int i = (bid - 8) * 256 + t; i < zquads; i += (nb - 8) * 256)
            zbase[i] = make_float4(0.f, 0.f, 0.f, 0.f);
    }
    grid.sync();

    // ---- Phase B ----
    for (int i = t; i < 8 * INF; i += 256) uL[i >> 8][i & 255] = u[i];
    __syncthreads();
    {
        int wave = t >> 6, lane = t & 63;
        for (int n = bid * 4 + wave; n < N; n += nb * 4) {
            float4 xv = *(const float4*)(x + (size_t)n * INF + lane * 4);
            float p[8];
            #pragma unroll
            for (int c = 0; c < 8; ++c)
                p[c] = xv.x * uL[c][lane * 4]     + xv.y * uL[c][lane * 4 + 1]
                     + xv.z * uL[c][lane * 4 + 2] + xv.w * uL[c][lane * 4 + 3];
            #pragma unroll
            for (int c = 0; c < 8; ++c)
                #pragma unroll
                for (int off = 32; off; off >>= 1) p[c] += __shfl_down(p[c], off, 64);
            if (lane == 0) {
                ssrc[n] = make_float4(p[0], p[1], p[2], p[3]);
                sdst[n] = make_float4(p[4], p[5], p[6], p[7]);
            }
        }
    }
    for (int e = bid * 256 + t; e < E; e += nb * 256) {
        int s = src[e];
        if (s == dst[e]) flag[s] = 1;   // benign race: same value
    }
    grid.sync();

    // ---- Phase C ----
    for (int e = bid * 256 + t; e < E; e += nb * 256) {
        int d = dst[e];
        if (!flag[d]) continue;
        int s = src[e];
        float4 sa = ssrc[s], sb = sdst[d];
        float eh[4] = {sa.x + sb.x, sa.y + sb.y, sa.z + sb.z, sa.w + sb.w};
        bool selfe = (s == d);
        #pragma unroll
        for (int h = 0; h < 4; ++h) {
            float z = eh[h];
            z = z > 0.f ? z : NEG_SLOPE * z;
            float w = expf(z);
            atomicAdd(&denom[d * 4 + h], w);
            if (selfe) atomicAdd(&wsum[d * 4 + h], w);
        }
    }
    grid.sync();

    // ---- Phase D ----
    for (int n = bid; n < N; n += nb) {
        if (flag[n]) {                               // block-uniform branch
            float4 wv = *(const float4*)(wsum  + (size_t)n * 4);
            float4 dv = *(const float4*)(denom + (size_t)n * 4);
            float d0 = wv.x / (dv.x + 1e-16f), d1 = wv.y / (dv.y + 1e-16f);
            float d2 = wv.z / (dv.z + 1e-16f), d3 = wv.w / (dv.w + 1e-16f);
            __syncthreads();
            xL[t] = x[(size_t)n * INF + t];
            __syncthreads();
            int h = t >> 6, o = (2 * t) & 127;
            float dg = (h == 0) ? d0 : (h == 1) ? d1 : (h == 2) ? d2 : d3;
            const float* Wc = W + (size_t)h * INF * OUTF + o;
            float acc0 = 0.f, acc1 = 0.f;
            #pragma unroll 8
            for (int i = 0; i < INF; ++i) {
                float xi = xL[i];
                acc0 += xi * Wc[(size_t)i * OUTF];
                acc1 += xi * Wc[(size_t)i * OUTF + 1];
            }
            out2[(size_t)n * 256 + t] = make_float2(dg * acc0, dg * acc1);
        } else {
            out2[(size_t)n * 256 + t] = make_float2(0.f, 0.f);
        }
    }
}

// ============================ fallback path (round-4, proven) ============================
__global__ void k1_init(const float* __restrict__ W, const float* __restrict__ a,
                        float* __restrict__ u, float4* __restrict__ zbase, int zquads) {
    if (blockIdx.x < 8) {
        int c = blockIdx.x, kind = c >> 2, h = c & 3;
        __shared__ float av[OUTF];
        int t = threadIdx.x;
        if (t < OUTF) av[t] = a[h * 2 * OUTF + kind * OUTF + t];
        __syncthreads();
        const float* Wr = W + ((size_t)(h * INF + t)) * OUTF;
        float acc = 0.f;
        #pragma unroll 8
        for (int o = 0; o < OUTF; ++o) acc += Wr[o] * av[o];
        u[c * INF + t] = acc;
    } else {
        int i = (blockIdx.x - 8) * blockDim.x + threadIdx.x;
        if (i < zquads) zbase[i] = make_float4(0.f, 0.f, 0.f, 0.f);
    }
}

__global__ void k2_s_scan(const float* __restrict__ x, const float* __restrict__ u,
                          const int* __restrict__ src, const int* __restrict__ dst,
                          int N, int E, int sBlocks,
                          float4* __restrict__ s_src, float4* __restrict__ s_dst,
                          int* __restrict__ flag) {
    if (blockIdx.x < sBlocks) {
        __shared__ float uL[8][INF];
        for (int i = threadIdx.x; i < 8 * INF; i += blockDim.x)
            uL[i >> 8][i & 255] = u[i];
        __syncthreads();
        int wave = threadIdx.x >> 6, lane = threadIdx.x & 63;
        int n = blockIdx.x * 4 + wave;
        if (n >= N) return;
        float4 xv = *(const float4*)(x + (size_t)n * INF + lane * 4);
        float p[8];
        #pragma unroll
        for (int c = 0; c < 8; ++c)
            p[c] = xv.x * uL[c][lane * 4]     + xv.y * uL[c][lane * 4 + 1]
                 + xv.z * uL[c][lane * 4 + 2] + xv.w * uL[c][lane * 4 + 3];
        #pragma unroll
        for (int c = 0; c < 8; ++c)
            #pragma unroll
            for (int off = 32; off; off >>= 1) p[c] += __shfl_down(p[c], off, 64);
        if (lane == 0) {
            s_src[n] = make_float4(p[0], p[1], p[2], p[3]);
            s_dst[n] = make_float4(p[4], p[5], p[6], p[7]);
        }
    } else {
        int e = (blockIdx.x - sBlocks) * blockDim.x + threadIdx.x;
        if (e < E) {
            int s = src[e];
            if (s == dst[e]) flag[s] = 1;
        }
    }
}

__global__ void k3_denom(const int* __restrict__ src, const int* __restrict__ dst, int E,
                         const int* __restrict__ flag,
                         const float4* __restrict__ s_src, const float4* __restrict__ s_dst,
                         float* __restrict__ denom, float* __restrict__ wsum) {
    int e = blockIdx.x * blockDim.x + threadIdx.x;
    if (e >= E) return;
    int d = dst[e];
    if (!flag[d]) return;
    int s = src[e];
    float4 sa = s_src[s], sb = s_dst[d];
    float eh[4] = {sa.x + sb.x, sa.y + sb.y, sa.z + sb.z, sa.w + sb.w};
    bool selfe = (s == d);
    #pragma unroll
    for (int h = 0; h < 4; ++h) {
        float z = eh[h];
        z = z > 0.f ? z : NEG_SLOPE * z;
        float w = expf(z);
        atomicAdd(&denom[d * 4 + h], w);
        if (selfe) atomicAdd(&wsum[d * 4 + h], w);
    }
}

__global__ __launch_bounds__(256)
void k4_out(const float* __restrict__ x, const float* __restrict__ W,
            const float* __restrict__ denom, const float* __restrict__ wsum,
            float2* __restrict__ out2, int N, int nodesPerBlock) {
    __shared__ float xL[INF];
    int n0 = blockIdx.x * nodesPerBlock;
    int n1 = n0 + nodesPerBlock; if (n1 > N) n1 = N;
    int t = threadIdx.x;
    for (int n = n0; n < n1; ++n) {
        float4 wv = *(const float4*)(wsum + (size_t)n * 4);
        bool flg = (wv.x != 0.f) | (wv.y != 0.f) | (wv.z != 0.f) | (wv.w != 0.f);
        if (flg) {
            float4 dv = *(const float4*)(denom + (size_t)n * 4);
            float d0 = wv.x / (dv.x + 1e-16f), d1 = wv.y / (dv.y + 1e-16f);
            float d2 = wv.z / (dv.z + 1e-16f), d3 = wv.w / (dv.w + 1e-16f);
            __syncthreads();
            xL[t] = x[(size_t)n * INF + t];
            __syncthreads();
            int h = t >> 6, o = (2 * t) & 127;
            float dg = (h == 0) ? d0 : (h == 1) ? d1 : (h == 2) ? d2 : d3;
            const float* Wc = W + (size_t)h * INF * OUTF + o;
            float acc0 = 0.f, acc1 = 0.f;
            #pragma unroll 8
            for (int i = 0; i < INF; ++i) {
                float xi = xL[i];
                acc0 += xi * Wc[(size_t)i * OUTF];
                acc1 += xi * Wc[(size_t)i * OUTF + 1];
            }
            out2[(size_t)n * 256 + t] = make_float2(dg * acc0, dg * acc1);
        } else {
            out2[(size_t)n * 256 + t] = make_float2(0.f, 0.f);
        }
    }
}

extern "C" void kernel_launch(void* const* d_in, const int* in_sizes, int n_in,
                              void* d_out, int out_size, void* d_ws, size_t ws_size,
                              hipStream_t stream) {
    const float* x = (const float*)d_in[0];
    const float* W = (const float*)d_in[1];
    const float* a = (const float*)d_in[2];
    const int* ei = (const int*)d_in[3];
    int N = in_sizes[0] / INF;     // 15000
    int E = in_sizes[3] / 2;       // 720000
    const int* src = ei;
    const int* dst = ei + E;

    char* ws = (char*)d_ws;
    float*  u    = (float*)ws;                                   // 8 KB
    float4* ssrc = (float4*)(ws + 8192);                         // 16N
    float4* sdst = (float4*)(ws + 8192 + (size_t)N * 16);        // 16N
    size_t zoff  = 8192 + (size_t)N * 32;                        // 16B aligned
    float*  denom = (float*)(ws + zoff);                         // 16N
    float*  wsum  = (float*)(ws + zoff + (size_t)N * 16);        // 16N
    int*    flag  = (int*)  (ws + zoff + (size_t)N * 32);        // 4N
    float4* zbase = (float4*)(ws + zoff);
    int zquads = (int)(((size_t)N * 36 + 15) / 16);
    float2* out2 = (float2*)d_out;

    // ---- try single cooperative dispatch, sized by the runtime's own occupancy ----
    bool coop_ok = false;
    int blocksPerCU = 0;
    hipError_t qerr = hipOccupancyMaxActiveBlocksPerMultiprocessor(
        &blocksPerCU, (const void*)k_fused, 256, 0);
    if (qerr == hipSuccess && blocksPerCU >= 1) {
        int NB = blocksPerCU * 256;          // 256 CUs on MI355X
        if (NB > 1024) NB = 1024;
        if (NB >= 16) {
            void* args[] = {
                (void*)&x, (void*)&W, (void*)&a, (void*)&src, (void*)&dst,
                (void*)&N, (void*)&E,
                (void*)&u, (void*)&ssrc, (void*)&sdst,
                (void*)&denom, (void*)&wsum, (void*)&flag,
                (void*)&zbase, (void*)&zquads, (void*)&out2,
            };
            hipError_t lerr = hipLaunchCooperativeKernel(
                (const void*)k_fused, dim3(NB), dim3(256), args, 0, stream);
            coop_ok = (lerr == hipSuccess);
        }
    }
    (void)hipGetLastError();   // clear any sticky error from a failed attempt

    if (!coop_ok) {
        // ---- proven 4-kernel fallback (round 4) ----
        int zblocks = (zquads + 255) / 256;
        k1_init<<<8 + zblocks, 256, 0, stream>>>(W, a, u, zbase, zquads);
        int sBlocks = (N + 3) / 4;
        int eBlocks = (E + 255) / 256;
        k2_s_scan<<<sBlocks + eBlocks, 256, 0, stream>>>(x, u, src, dst, N, E, sBlocks,
                                                         ssrc, sdst, flag);
        k3_denom<<<eBlocks, 256, 0, stream>>>(src, dst, E, flag, ssrc, sdst, denom, wsum);
        int nodesPerBlock = 8;
        int oBlocks = (N + nodesPerBlock - 1) / nodesPerBlock;
        k4_out<<<oBlocks, 256, 0, stream>>>(x, W, denom, wsum, out2, N, nodesPerBlock);
    }
}

// Round 7
// 56.387 us; speedup vs baseline: 5.5778x; 5.5778x over previous
//
#include <hip/hip_runtime.h>

#define INF 256
#define OUTF 128
#define NEG_SLOPE 0.2f

// ---------------- hand-rolled grid barrier (requires co-resident grid) ----------------
// Mirrors cg::grid.sync()'s fence structure (release fence -> arrive -> acquire spin)
// but with a single counter per barrier and short sleep, avoiding ROCm's ~110us sync.
__device__ __forceinline__ void gbar(unsigned int* cnt, unsigned int target) {
    __syncthreads();
    if (threadIdx.x == 0) {
        __threadfence();  // release: write back this block's stores to coherence point
        __hip_atomic_fetch_add(cnt, 1u, __ATOMIC_RELEASE, __HIP_MEMORY_SCOPE_AGENT);
        while (__hip_atomic_load(cnt, __ATOMIC_ACQUIRE, __HIP_MEMORY_SCOPE_AGENT) < target)
            __builtin_amdgcn_s_sleep(8);
        __threadfence();  // acquire: invalidate stale L1/L2 before post-barrier reads
    }
    __syncthreads();
}

// ---------------- K1 (normal): u = W@a  +  zero [denom|wsum|flag|counters] ----------------
__global__ void k1_init(const float* __restrict__ W, const float* __restrict__ a,
                        float* __restrict__ u, float4* __restrict__ zbase, int zquads) {
    if (blockIdx.x < 8) {
        int c = blockIdx.x, kind = c >> 2, h = c & 3;
        __shared__ float av[OUTF];
        int t = threadIdx.x;
        if (t < OUTF) av[t] = a[h * 2 * OUTF + kind * OUTF + t];
        __syncthreads();
        const float* Wr = W + ((size_t)(h * INF + t)) * OUTF;
        float acc = 0.f;
        #pragma unroll 8
        for (int o = 0; o < OUTF; ++o) acc += Wr[o] * av[o];
        u[c * INF + t] = acc;
    } else {
        int i = (blockIdx.x - 8) * blockDim.x + threadIdx.x;
        if (i < zquads) zbase[i] = make_float4(0.f, 0.f, 0.f, 0.f);
    }
}

// ---------------- K2 (cooperative): P0 {s-sweep + flag scan} | bar | P1 {denom} | bar | P2 {out} ----
__global__ __launch_bounds__(1024)
void k_fused2(const float* __restrict__ x, const float* __restrict__ W,
              const int* __restrict__ src, const int* __restrict__ dst,
              int N, int E,
              const float* __restrict__ u,
              float4* __restrict__ ssrc, float4* __restrict__ sdst,
              float* __restrict__ denom, float* __restrict__ wsum,
              int* __restrict__ flag, unsigned int* __restrict__ cnt,
              float2* __restrict__ out2) {
    const int bid = blockIdx.x, nb = gridDim.x, t = threadIdx.x;
    __shared__ float uL[8][INF];

    // ---- P0a: s_src/s_dst for all nodes (one wave per node) ----
    for (int i = t; i < 8 * INF; i += 1024) uL[i >> 8][i & 255] = u[i];
    __syncthreads();
    {
        int wave = t >> 6, lane = t & 63;
        for (int n = bid * 16 + wave; n < N; n += nb * 16) {
            float4 xv = *(const float4*)(x + (size_t)n * INF + lane * 4);
            float p[8];
            #pragma unroll
            for (int c = 0; c < 8; ++c)
                p[c] = xv.x * uL[c][lane * 4]     + xv.y * uL[c][lane * 4 + 1]
                     + xv.z * uL[c][lane * 4 + 2] + xv.w * uL[c][lane * 4 + 3];
            #pragma unroll
            for (int c = 0; c < 8; ++c)
                #pragma unroll
                for (int off = 32; off; off >>= 1) p[c] += __shfl_down(p[c], off, 64);
            if (lane == 0) {
                ssrc[n] = make_float4(p[0], p[1], p[2], p[3]);
                sdst[n] = make_float4(p[4], p[5], p[6], p[7]);
            }
        }
    }
    // ---- P0b: self-loop scan (flag was zeroed by K1, prior dispatch) ----
    for (int e = bid * 1024 + t; e < E; e += nb * 1024) {
        int s = src[e];
        if (s == dst[e]) flag[s] = 1;   // benign race: same value
    }
    gbar(&cnt[0], (unsigned int)nb);

    // ---- P1: denom/wsum for edges whose dst has a self-loop (~0.3%) ----
    for (int e = bid * 1024 + t; e < E; e += nb * 1024) {
        int d = dst[e];
        if (!flag[d]) continue;
        int s = src[e];
        float4 sa = ssrc[s], sb = sdst[d];
        float eh[4] = {sa.x + sb.x, sa.y + sb.y, sa.z + sb.z, sa.w + sb.w};
        bool selfe = (s == d);
        #pragma unroll
        for (int h = 0; h < 4; ++h) {
            float z = eh[h];
            z = z > 0.f ? z : NEG_SLOPE * z;
            float w = expf(z);
            atomicAdd(&denom[d * 4 + h], w);
            if (selfe) atomicAdd(&wsum[d * 4 + h], w);
        }
    }
    gbar(&cnt[1], (unsigned int)nb);

    // ---- P2: write ENTIRE output; flagged rows (~48) via on-the-fly GEMV ----
    {
        int sub = t >> 8, st = t & 255;               // 4 sub-rows of 256 threads
        for (int n = bid * 4 + sub; n < N; n += nb * 4) {
            if (flag[n]) {
                int h = st >> 6, o = (2 * st) & 127;
                float dg = wsum[n * 4 + h] / (denom[n * 4 + h] + 1e-16f);
                const float* xr = x + (size_t)n * INF;
                const float* Wc = W + (size_t)h * INF * OUTF + o;
                float acc0 = 0.f, acc1 = 0.f;
                #pragma unroll 8
                for (int i = 0; i < INF; ++i) {       // x reads wave-uniform -> broadcast, L2-hit
                    float xi = xr[i];
                    acc0 += xi * Wc[(size_t)i * OUTF];
                    acc1 += xi * Wc[(size_t)i * OUTF + 1];
                }
                out2[(size_t)n * 256 + st] = make_float2(dg * acc0, dg * acc1);
            } else {
                out2[(size_t)n * 256 + st] = make_float2(0.f, 0.f);
            }
        }
    }
}

// ---------------- fallback path (round-4, proven ~56us) ----------------
__global__ void k2_s_scan(const float* __restrict__ x, const float* __restrict__ u,
                          const int* __restrict__ src, const int* __restrict__ dst,
                          int N, int E, int sBlocks,
                          float4* __restrict__ s_src, float4* __restrict__ s_dst,
                          int* __restrict__ flag) {
    if (blockIdx.x < sBlocks) {
        __shared__ float uL[8][INF];
        for (int i = threadIdx.x; i < 8 * INF; i += blockDim.x)
            uL[i >> 8][i & 255] = u[i];
        __syncthreads();
        int wave = threadIdx.x >> 6, lane = threadIdx.x & 63;
        int n = blockIdx.x * 4 + wave;
        if (n >= N) return;
        float4 xv = *(const float4*)(x + (size_t)n * INF + lane * 4);
        float p[8];
        #pragma unroll
        for (int c = 0; c < 8; ++c)
            p[c] = xv.x * uL[c][lane * 4]     + xv.y * uL[c][lane * 4 + 1]
                 + xv.z * uL[c][lane * 4 + 2] + xv.w * uL[c][lane * 4 + 3];
        #pragma unroll
        for (int c = 0; c < 8; ++c)
            #pragma unroll
            for (int off = 32; off; off >>= 1) p[c] += __shfl_down(p[c], off, 64);
        if (lane == 0) {
            s_src[n] = make_float4(p[0], p[1], p[2], p[3]);
            s_dst[n] = make_float4(p[4], p[5], p[6], p[7]);
        }
    } else {
        int e = (blockIdx.x - sBlocks) * blockDim.x + threadIdx.x;
        if (e < E) {
            int s = src[e];
            if (s == dst[e]) flag[s] = 1;
        }
    }
}

__global__ void k3_denom(const int* __restrict__ src, const int* __restrict__ dst, int E,
                         const int* __restrict__ flag,
                         const float4* __restrict__ s_src, const float4* __restrict__ s_dst,
                         float* __restrict__ denom, float* __restrict__ wsum) {
    int e = blockIdx.x * blockDim.x + threadIdx.x;
    if (e >= E) return;
    int d = dst[e];
    if (!flag[d]) return;
    int s = src[e];
    float4 sa = s_src[s], sb = s_dst[d];
    float eh[4] = {sa.x + sb.x, sa.y + sb.y, sa.z + sb.z, sa.w + sb.w};
    bool selfe = (s == d);
    #pragma unroll
    for (int h = 0; h < 4; ++h) {
        float z = eh[h];
        z = z > 0.f ? z : NEG_SLOPE * z;
        float w = expf(z);
        atomicAdd(&denom[d * 4 + h], w);
        if (selfe) atomicAdd(&wsum[d * 4 + h], w);
    }
}

__global__ __launch_bounds__(256)
void k4_out(const float* __restrict__ x, const float* __restrict__ W,
            const float* __restrict__ denom, const float* __restrict__ wsum,
            float2* __restrict__ out2, int N, int nodesPerBlock) {
    __shared__ float xL[INF];
    int n0 = blockIdx.x * nodesPerBlock;
    int n1 = n0 + nodesPerBlock; if (n1 > N) n1 = N;
    int t = threadIdx.x;
    for (int n = n0; n < n1; ++n) {
        float4 wv = *(const float4*)(wsum + (size_t)n * 4);
        bool flg = (wv.x != 0.f) | (wv.y != 0.f) | (wv.z != 0.f) | (wv.w != 0.f);
        if (flg) {
            float4 dv = *(const float4*)(denom + (size_t)n * 4);
            float d0 = wv.x / (dv.x + 1e-16f), d1 = wv.y / (dv.y + 1e-16f);
            float d2 = wv.z / (dv.z + 1e-16f), d3 = wv.w / (dv.w + 1e-16f);
            __syncthreads();
            xL[t] = x[(size_t)n * INF + t];
            __syncthreads();
            int h = t >> 6, o = (2 * t) & 127;
            float dg = (h == 0) ? d0 : (h == 1) ? d1 : (h == 2) ? d2 : d3;
            const float* Wc = W + (size_t)h * INF * OUTF + o;
            float acc0 = 0.f, acc1 = 0.f;
            #pragma unroll 8
            for (int i = 0; i < INF; ++i) {
                float xi = xL[i];
                acc0 += xi * Wc[(size_t)i * OUTF];
                acc1 += xi * Wc[(size_t)i * OUTF + 1];
            }
            out2[(size_t)n * 256 + t] = make_float2(dg * acc0, dg * acc1);
        } else {
            out2[(size_t)n * 256 + t] = make_float2(0.f, 0.f);
        }
    }
}

extern "C" void kernel_launch(void* const* d_in, const int* in_sizes, int n_in,
                              void* d_out, int out_size, void* d_ws, size_t ws_size,
                              hipStream_t stream) {
    const float* x = (const float*)d_in[0];
    const float* W = (const float*)d_in[1];
    const float* a = (const float*)d_in[2];
    const int* ei = (const int*)d_in[3];
    int N = in_sizes[0] / INF;     // 15000
    int E = in_sizes[3] / 2;       // 720000
    const int* src = ei;
    const int* dst = ei + E;

    char* ws = (char*)d_ws;
    float*  u    = (float*)ws;                                   // 8 KB
    float4* ssrc = (float4*)(ws + 8192);                         // 16N
    float4* sdst = (float4*)(ws + 8192 + (size_t)N * 16);        // 16N
    size_t zoff  = 8192 + (size_t)N * 32;                        // 16B aligned
    float*  denom = (float*)(ws + zoff);                         // 16N
    float*  wsum  = (float*)(ws + zoff + (size_t)N * 16);        // 16N
    int*    flag  = (int*)  (ws + zoff + (size_t)N * 32);        // 4N
    unsigned int* cnt = (unsigned int*)(ws + zoff + (size_t)N * 36); // 2 barrier counters
    float4* zbase = (float4*)(ws + zoff);
    int zquads = (int)(((size_t)N * 36 + 16 + 15) / 16);         // covers counters too
    float2* out2 = (float2*)d_out;

    // K1: u + zeroing (also zeroes barrier counters — prior dispatch, so no race)
    int zblocks = (zquads + 255) / 256;
    k1_init<<<8 + zblocks, 256, 0, stream>>>(W, a, u, zbase, zquads);

    // K2: try single cooperative dispatch with hand-rolled barriers
    bool coop_ok = false;
    int blocksPerCU = 0;
    hipError_t qerr = hipOccupancyMaxActiveBlocksPerMultiprocessor(
        &blocksPerCU, (const void*)k_fused2, 1024, 0);
    if (qerr == hipSuccess && blocksPerCU >= 1) {
        int NB = 256;   // 1 block/CU target; co-residency guaranteed by coop launch
        void* args[] = {
            (void*)&x, (void*)&W, (void*)&src, (void*)&dst,
            (void*)&N, (void*)&E, (void*)&u,
            (void*)&ssrc, (void*)&sdst, (void*)&denom, (void*)&wsum,
            (void*)&flag, (void*)&cnt, (void*)&out2,
        };
        hipError_t lerr = hipLaunchCooperativeKernel(
            (const void*)k_fused2, dim3(NB), dim3(1024), args, 0, stream);
        coop_ok = (lerr == hipSuccess);
    }
    (void)hipGetLastError();   // clear sticky error from a failed attempt

    if (!coop_ok) {
        // proven 4-kernel fallback
        int sBlocks = (N + 3) / 4;
        int eBlocks = (E + 255) / 256;
        k2_s_scan<<<sBlocks + eBlocks, 256, 0, stream>>>(x, u, src, dst, N, E, sBlocks,
                                                         ssrc, sdst, flag);
        k3_denom<<<eBlocks, 256, 0, stream>>>(src, dst, E, flag, ssrc, sdst, denom, wsum);
        int nodesPerBlock = 8;
        int oBlocks = (N + nodesPerBlock - 1) / nodesPerBlock;
        k4_out<<<oBlocks, 256, 0, stream>>>(x, W, denom, wsum, out2, N, nodesPerBlock);
    }
}